// Round 14
// baseline (820.682 us; speedup 1.0000x reference)
//
#include <hip/hip_runtime.h>
#include <math.h>

#define NN 4096
#define STRIPS 32
#define SW 128                        // strip width (columns per workgroup)
#define RING_ROWS 256                 // power of 2: slot = row & 255
#define BATCH 32
#define NBATCH 130                    // (NN + 64) / BATCH
#define PAD 64                        // colbuf per-strip padding rows
#define COLPITCH (NN + 2 * PAD)
#define INFV 1e30f
#define SENTU 0xFFFFFFFFu             // memset(0xFF) sentinel, never a DP result

// lane l <- lane l-1 (whole-wave shift right by 1), VALU-latency cross-lane move
__device__ __forceinline__ float dpp_wave_shr1(float x) {
    return __int_as_float(__builtin_amdgcn_update_dpp(
        0, __float_as_int(x), 0x138 /*WAVE_SHR1*/, 0xf, 0xf, false));
}

// lanes 0..31 load one boundary row each (clamped): exactly 1 vmem instruction
__device__ __forceinline__ float bload(const unsigned* colL, int row, int lane) {
    float v = INFV;
    const int rowc = (row < NN) ? row : (NN - 1);
    if (lane < 32) {
        unsigned u = __hip_atomic_load(colL + rowc, __ATOMIC_RELAXED,
                                       __HIP_MEMORY_SCOPE_AGENT);
        v = __uint_as_float(u);
    }
    return v;
}

// rows [rb, rb+32) still hold the memset sentinel? (rows >= NN masked off)
__device__ __forceinline__ bool has_sent(float b, int rb, int lane) {
    return __any((lane < 32) && ((rb + lane) < NN) &&
                 (__float_as_uint(b) == SENTU));
}

// async-stage rows [rb, rb+32) into the LDS ring at slot (row&255).
// ALWAYS exactly 16 global_load_lds (src rows clamped; slot from UNCLAMPED row)
__device__ __forceinline__ void stageB(const float* Sg, float* ring, int rb,
                                       int lane) {
    #pragma unroll
    for (int k = 0; k < 16; ++k) {
        const int r0 = rb + 2 * k;
        const int r0c = (r0 < NN - 1) ? r0 : (NN - 2);
        const int slot = r0 & (RING_ROWS - 1);
        const float* gsrc =
            Sg + (size_t)(r0c + (lane >> 5)) * NN + ((lane & 31) << 2);
        __builtin_amdgcn_global_load_lds(
            (const __attribute__((address_space(1))) unsigned*)gsrc,
            (__attribute__((address_space(3))) unsigned*)((char*)ring +
                                                         slot * (SW * 4)),
            16, 0, 0);
    }
}

// lgkmcnt is a 4-bit field on gfx950: N must be 0..15.
#define WAITL(N) do {                                                   \
    __builtin_amdgcn_sched_barrier(0);                                  \
    asm volatile("s_waitcnt lgkmcnt(" #N ")" ::: "memory");             \
    __builtin_amdgcn_sched_barrier(0); } while (0)

// issue 8 ds_reads for one cluster into a NAMED register buffer (static idx)
#define CL_ISSUE(BUF, RB) do {                                          \
    _Pragma("unroll")                                                   \
    for (int k_ = 0; k_ < 8; ++k_) {                                    \
        const int row_ = (RB) + k_;                                     \
        const unsigned ad_ = (((unsigned)(row_ & 255)) << 9) |          \
                             ((unsigned)lane << 3);                     \
        BUF[k_] = *reinterpret_cast<const float2*>(                     \
            (const char*)ring + ad_);                                   \
    }                                                                   \
    __builtin_amdgcn_sched_barrier(0); } while (0)

// 8-row chain on a cluster buffer. MODE 2: constants (no reads);
// MODE 3: read-dependent passthrough (no serial chain).
#define CL_CHAIN(BUF, CB) do {                                          \
    _Pragma("unroll")                                                   \
    for (int k_ = 0; k_ < 8; ++k_) {                                    \
        const int s_ = (CB) + k_;                                       \
        const float e0 = (MODE == 2) ? 1.0f : BUF[k_].x;                \
        const float e1 = (MODE == 2) ? 1.0f : BUF[k_].y;                \
        if (MODE == 3) {                                                \
            const float c1 = e0 + e1;                                   \
            *obp = c1; obp += ostep;                                    \
            if (s_ == 30) save = c1;                                    \
        } else {                                                        \
            float bcur;                                                 \
            if (G0) bcur = (n == 0 && s_ == 0) ? 0.f : INFV;            \
            else bcur = __int_as_float(                                 \
                __builtin_amdgcn_readlane(__float_as_int(binb), s_));   \
            const float bpv = G0 ? INFV : ((s_ == 0) ? bprevc : pbc);   \
            const float L1 = lane0 ? bcur : l1s;                        \
            const float L2 = lane0 ? bpv : l2s;                         \
            const float m0 = fminf(fminf(L1, cur0), L2);                \
            const float c0 = e0 + m0;                                   \
            const float c1 = e1 + fminf(c0, fminf(cur0, cur1));         \
            *obp = c1; obp += ostep;                                    \
            const float sh = dpp_wave_shr1(c1);                         \
            l2s = l1s; l1s = sh;                                        \
            cur0 = c0; cur1 = c1;                                       \
            pbc = bcur;                                                 \
            if (s_ == 30) save = c1;                                    \
        }                                                               \
    } } while (0)

// ---------------------------------------------------------------------------
// 2-wave producer/consumer DP, cluster-pipelined LDS reads.
// MODE 0: real. MODE 1: free-run (no comm). MODE 2: free-run, no ds_reads.
// MODE 3: free-run, no serial chain (reads kept live via publish dependency).
//
// Compute wave, per batch (4 clusters x 8 rows, bufA/bufB = 32 VGPRs):
//   [ISSUE c1][lgkm(8)][CHAIN c0][ISSUE c2][lgkm(15)][CHAIN c1]
//   [ISSUE c3][lgkm(15)][CHAIN c2][lgkm(8)][CHAIN c3][lgkm(0)]
//   [outbox -> half-wave agent store publishes rows [tb-63, tb-32]]
//   [ISSUE next batch's c0][barrier]
// Wait derivation (in-order DS retirement): at the lgkm(15) points the needed
// cluster's 8 reads have exactly 16 newer DS ops (8 outbox writes + 8 just-
// issued reads); outstanding<=15 implies <=16 -> retired. Conservative-safe.
// Cross-batch c0 prefetch reads rows staged 3 batches ahead, landing-proven
// at the PREVIOUS barrier by support's counted vmcnt.
// Support wave, per batch: validate boundary rows [tb+32,tb+64) -> inbox;
//   prefetch qv [tb+64,tb+96); stage rows [tb+96,tb+128) (batch n+3);
//   vmcnt(17|16) counted; lgkm(0); barrier.
// ---------------------------------------------------------------------------
template <int MODE>
__global__ __launch_bounds__(128, 1) void dtw_dp(const float* __restrict__ E,
                                                 float* __restrict__ cost_out,
                                                 unsigned* __restrict__ colbuf) {
    __shared__ float ring[RING_ROWS * SW];   // 128 KB
    __shared__ float inbox[2][32];
    __shared__ float outbox[32];
    __shared__ float outdummy[64];

    const int tid = threadIdx.x;
    const int lane = tid & 63;
    const int b = blockIdx.x;
    const int g = ((b & 7) << 2) | (b >> 3);   // XCD-affinity strip remap

    const float* Eg = E + g * SW;
    const unsigned* colL = colbuf + (size_t)(g - 1) * COLPITCH + PAD;
    unsigned* colM = colbuf + (size_t)g * COLPITCH + PAD;
    const bool comm = (MODE == 0) && (g > 0);
    const bool G0 = (MODE == 0) && (g == 0);

    if (tid < 64) {
        // ================= compute wave =================
        // clear pre-start ring slots [192,256): rows r<0 read 0 (INF+0=INF)
        {
            const float4 z = make_float4(0.f, 0.f, 0.f, 0.f);
            float4* r4 = reinterpret_cast<float4*>(&ring[192 * SW]);
            #pragma unroll
            for (int i = 0; i < 32; ++i) r4[i * 64 + lane] = z;
        }
        asm volatile("s_waitcnt lgkmcnt(0)" ::: "memory");
        __builtin_amdgcn_s_barrier();   // prologue barrier

        const bool lane0 = (lane == 0);
        const int ostep = (lane == 63) ? 1 : 0;
        float cur0 = INFV, cur1 = INFV;   // my c[r-1][2l], c[r-1][2l+1]
        float l1s = INFV, l2s = INFV;     // lane l-1's c1 from t-1, t-2
        float bprevc = INFV;              // boundary carry (row tb-1)
        float save = 0.f;
        float2 bufA[8], bufB[8];

        if (MODE != 2) CL_ISSUE(bufA, 0 - lane);   // batch 0 cluster 0

        for (int n = 0; n < NBATCH; ++n) {
            const int tb = n << 5;
            const int rowb = tb - lane;
            const float binb = inbox[n & 1][lane & 31];
            float* obp = (lane == 63) ? &outbox[0] : &outdummy[lane];
            float pbc = INFV;

            if (MODE != 2) CL_ISSUE(bufB, rowb + 8);
            WAITL(8);  CL_CHAIN(bufA, 0);
            if (MODE != 2) CL_ISSUE(bufA, rowb + 16);
            WAITL(15); CL_CHAIN(bufB, 8);
            if (MODE != 2) CL_ISSUE(bufB, rowb + 24);
            WAITL(15); CL_CHAIN(bufA, 16);
            WAITL(8);  CL_CHAIN(bufB, 24);
            bprevc = pbc;
            WAITL(0);   // outbox (lane63's 32 ds_writes) complete
            {
                const float ob = outbox[lane & 31];
                if (lane < 32)
                    __hip_atomic_store(colM + (tb - 63 + lane),
                                       __float_as_uint(ob), __ATOMIC_RELAXED,
                                       __HIP_MEMORY_SCOPE_AGENT);
            }
            if (MODE != 2) CL_ISSUE(bufA, rowb + 32);  // next batch cluster 0
            __builtin_amdgcn_s_barrier();
        }
        if (g == STRIPS - 1 && lane == 63) cost_out[0] = save;
    } else {
        // ================= support wave =================
        stageB(Eg, ring, 0, lane);    // rows [0,32)   batch 0
        stageB(Eg, ring, 32, lane);   // rows [32,64)  batch 1
        stageB(Eg, ring, 64, lane);   // rows [64,96)  batch 2
        float qv = INFV;
        if (comm) {
            qv = bload(colL, lane & 31, lane);
            while (has_sent(qv, 0, lane)) qv = bload(colL, lane & 31, lane);
            if (lane < 32) inbox[0][lane] = qv;
            qv = bload(colL, 32 + (lane & 31), lane);   // rows [32,64)
        }
        asm volatile("s_waitcnt vmcnt(0) lgkmcnt(0)" ::: "memory");
        __builtin_amdgcn_s_barrier();   // prologue barrier

        for (int n = 0; n < NBATCH; ++n) {
            const int tb = n << 5;
            if (comm) {
                // validate rows [tb+32, tb+64) (compute batch n+1's inbox)
                const int vb = tb + 32;
                while (has_sent(qv, vb, lane))
                    qv = bload(colL, vb + (lane & 31), lane);
                if (lane < 32) inbox[(n + 1) & 1][lane] = qv;
                qv = bload(colL, tb + 64 + (lane & 31), lane);  // next val.
            }
            stageB(Eg, ring, tb + 96, lane);   // rows for compute batch n+3
            __builtin_amdgcn_sched_barrier(0);
            // counted: newest 17 (16 no-comm) = THIS batch's qv+stage ->
            // batch n-1's stage (rows [tb+64,tb+96)) proven landed.
            if (comm) asm volatile("s_waitcnt vmcnt(17)" ::: "memory");
            else      asm volatile("s_waitcnt vmcnt(16)" ::: "memory");
            __builtin_amdgcn_sched_barrier(0);
            asm volatile("s_waitcnt lgkmcnt(0)" ::: "memory");
            __builtin_amdgcn_s_barrier();
        }
    }
}

// ---------------------------------------------------------------------------
// Fused: E = exp(-D)  AND  acc_grad[i,j] = d[i+1,j+1]+d[i+1,j]+d[i,j+1]-d[i,j]
// with d = exp(-exp(-D)) (zero-padded bottom/right).
// ---------------------------------------------------------------------------
__global__ __launch_bounds__(256) void eg_kernel(const float* __restrict__ D,
                                                 float* __restrict__ E,
                                                 float* __restrict__ G) {
    const int idx = blockIdx.x * 256 + threadIdx.x;
    const int i = idx >> 10;
    const int j = (idx & 1023) << 2;
    if (i >= NN) return;

    const float* row0 = D + (size_t)i * NN + j;
    const bool hasR = (i + 1) < NN;
    const bool hasC = (j + 4) < NN;

    const float4 r0 = *reinterpret_cast<const float4*>(row0);
    float4 r1 = make_float4(0.f, 0.f, 0.f, 0.f);
    if (hasR) r1 = *reinterpret_cast<const float4*>(row0 + NN);
    const float s0 = hasC ? row0[4] : 0.f;
    const float s1 = (hasR && hasC) ? row0[NN + 4] : 0.f;

    const float ex0 = __expf(-r0.x), ex1 = __expf(-r0.y);
    const float ex2 = __expf(-r0.z), ex3 = __expf(-r0.w);
    *reinterpret_cast<float4*>(E + (size_t)i * NN + j) =
        make_float4(ex0, ex1, ex2, ex3);

    const float a0 = __expf(-ex0), a1 = __expf(-ex1);
    const float a2 = __expf(-ex2), a3 = __expf(-ex3);
    const float a4 = hasC ? __expf(-__expf(-s0)) : 0.f;
    const float b0 = hasR ? __expf(-__expf(-r1.x)) : 0.f;
    const float b1 = hasR ? __expf(-__expf(-r1.y)) : 0.f;
    const float b2 = hasR ? __expf(-__expf(-r1.z)) : 0.f;
    const float b3 = hasR ? __expf(-__expf(-r1.w)) : 0.f;
    const float b4 = (hasR && hasC) ? __expf(-__expf(-s1)) : 0.f;

    float* go = G + (size_t)i * NN + j;
    go[0] = b1 + b0 + a1 - a0;
    go[1] = b2 + b1 + a2 - a1;
    go[2] = b3 + b2 + a3 - a2;
    go[3] = b4 + b3 + a4 - a3;
}

// fallback-path kernels (tiny ws): E into grad region, grad after DP
__global__ __launch_bounds__(256) void exp_pre(const float* __restrict__ D,
                                               float* __restrict__ E) {
    const int n4 = NN * NN / 4;
    for (int i = blockIdx.x * 256 + threadIdx.x; i < n4; i += 2048 * 256) {
        float4 v = reinterpret_cast<const float4*>(D)[i];
        v.x = __expf(-v.x); v.y = __expf(-v.y);
        v.z = __expf(-v.z); v.w = __expf(-v.w);
        reinterpret_cast<float4*>(E)[i] = v;
    }
}

__device__ __forceinline__ float dfun(float x) { return __expf(-__expf(-x)); }

__global__ __launch_bounds__(256) void dtw_grad_kernel(const float* __restrict__ D,
                                                       float* __restrict__ G) {
    const int idx = blockIdx.x * 256 + threadIdx.x;
    const int i = idx >> 10;
    const int j = (idx & 1023) << 2;
    if (i >= NN) return;

    const float* row0 = D + (size_t)i * NN + j;
    const bool hasR = (i + 1) < NN;
    const bool hasC = (j + 4) < NN;

    const float4 r0 = *reinterpret_cast<const float4*>(row0);
    float4 r1 = make_float4(0.f, 0.f, 0.f, 0.f);
    if (hasR) r1 = *reinterpret_cast<const float4*>(row0 + NN);
    const float s0 = hasC ? row0[4] : 0.f;
    const float s1 = (hasR && hasC) ? row0[NN + 4] : 0.f;

    const float a0 = dfun(r0.x), a1 = dfun(r0.y), a2 = dfun(r0.z), a3 = dfun(r0.w);
    const float a4 = hasC ? dfun(s0) : 0.f;
    const float b0 = hasR ? dfun(r1.x) : 0.f;
    const float b1 = hasR ? dfun(r1.y) : 0.f;
    const float b2 = hasR ? dfun(r1.z) : 0.f;
    const float b3 = hasR ? dfun(r1.w) : 0.f;
    const float b4 = (hasR && hasC) ? dfun(s1) : 0.f;

    float* go = G + (size_t)i * NN + j;
    go[0] = b1 + b0 + a1 - a0;
    go[1] = b2 + b1 + a2 - a1;
    go[2] = b3 + b2 + a3 - a2;
    go[3] = b4 + b3 + a4 - a3;
}

// ---------------------------------------------------------------------------
extern "C" void kernel_launch(void* const* d_in, const int* in_sizes, int n_in,
                              void* d_out, int out_size, void* d_ws, size_t ws_size,
                              hipStream_t stream) {
    (void)in_sizes; (void)n_in; (void)out_size;
    const float* D = (const float*)d_in[0];
    float* out = (float*)d_out;

    const size_t colbytes = (size_t)STRIPS * COLPITCH * sizeof(unsigned);
    const size_t ebytes = (size_t)NN * NN * sizeof(float);
    const int gblocks = (NN * (NN / 4)) / 256;

    if (ws_size >= ebytes + 2 * colbytes + 256) {
        // main path with probe dispatches (diagnostic round)
        float* E = (float*)d_ws;
        unsigned* colbuf = (unsigned*)((char*)d_ws + ebytes);
        unsigned* colbuf2 = (unsigned*)((char*)d_ws + ebytes + colbytes);
        float* costscr = (float*)((char*)d_ws + ebytes + 2 * colbytes);

        (void)hipMemsetAsync(colbuf, 0xFF, colbytes, stream);
        eg_kernel<<<gblocks, 256, 0, stream>>>(D, E, out + 1);
        dtw_dp<0><<<STRIPS, 128, 0, stream>>>(E, out, colbuf);       // REAL
        dtw_dp<1><<<STRIPS, 128, 0, stream>>>(E, costscr, colbuf2);  // free-run
        dtw_dp<2><<<STRIPS, 128, 0, stream>>>(E, costscr, colbuf2);  // no reads
        dtw_dp<3><<<STRIPS, 128, 0, stream>>>(E, costscr, colbuf2);  // no chain
    } else if (ws_size >= ebytes + colbytes) {
        float* E = (float*)d_ws;
        unsigned* colbuf = (unsigned*)((char*)d_ws + ebytes);
        (void)hipMemsetAsync(colbuf, 0xFF, colbytes, stream);
        eg_kernel<<<gblocks, 256, 0, stream>>>(D, E, out + 1);
        dtw_dp<0><<<STRIPS, 128, 0, stream>>>(E, out, colbuf);
    } else {
        // tiny-ws fallback: E lives in the grad region, grad runs after DP
        float* E = out + 1;
        unsigned* colbuf = (ws_size >= colbytes) ? (unsigned*)d_ws
                                                 : (unsigned*)(out + 1 + NN);
        (void)hipMemsetAsync(colbuf, 0xFF, colbytes, stream);
        exp_pre<<<2048, 256, 0, stream>>>(D, E);
        dtw_dp<0><<<STRIPS, 128, 0, stream>>>(E, out, colbuf);
        dtw_grad_kernel<<<gblocks, 256, 0, stream>>>(D, out + 1);
    }
}

// Round 15
// 730.966 us; speedup vs baseline: 1.1227x; 1.1227x over previous
//
#include <hip/hip_runtime.h>
#include <math.h>

#define NN 4096
#define STRIPS 32
#define SW 128                        // strip width (columns per workgroup)
#define BATCH 32
#define PAD 64                        // colbuf per-strip padding rows
#define COLPITCH (NN + 2 * PAD)
#define INFV 1e30f
#define SENTU 0xFFFFFFFFu             // memset(0xFF) sentinel, never a DP result

// lane l <- lane l-1 (whole-wave shift right by 1), VALU-latency cross-lane move
__device__ __forceinline__ float dpp_wave_shr1(float x) {
    return __int_as_float(__builtin_amdgcn_update_dpp(
        0, __float_as_int(x), 0x138 /*WAVE_SHR1*/, 0xf, 0xf, false));
}

// lanes 0..31 load one boundary row each (clamped): 1 vmem instruction
__device__ __forceinline__ float bload(const unsigned* colL, int row, int lane) {
    float v = INFV;
    const int rowc = (row < NN) ? row : (NN - 1);
    if (lane < 32) {
        unsigned u = __hip_atomic_load(colL + rowc, __ATOMIC_RELAXED,
                                       __HIP_MEMORY_SCOPE_AGENT);
        v = __uint_as_float(u);
    }
    return v;
}

// rows [rb, rb+32) still hold the memset sentinel? (rows >= NN masked off)
__device__ __forceinline__ bool has_sent(float b, int rb, int lane) {
    return __any((lane < 32) && ((rb + lane) < NN) &&
                 (__float_as_uint(b) == SENTU));
}

// issue 32 diagonal register loads: lane l gets (row RB+s-l, cols 2l,2l+1)
#define ELOAD(BUF, RB, CLAMP) do {                                          \
    _Pragma("unroll")                                                       \
    for (int s_ = 0; s_ < BATCH; ++s_) {                                    \
        int row_ = (RB) + s_ - lane;                                        \
        if (CLAMP) row_ = (row_ < 0) ? 0 : ((row_ > NN - 1) ? NN - 1 : row_);\
        BUF[s_] = *reinterpret_cast<const float2*>(                         \
            Sg + (size_t)row_ * NN + (lane << 1));                          \
    }                                                                       \
} while (0)

// one 32-row batch: validate boundary, prefetch next boundary, issue next
// batch's register loads, run the 32-step chain on CUR, publish lane63's rows
#define CSTEP(CUR, NXT, N, CLAMP) do {                                      \
    const int n_ = (N);                                                     \
    const int tb_ = n_ * BATCH;                                             \
    if (comm) {                                                             \
        while (has_sent(qv, tb_, lane))                                     \
            qv = bload(colL, tb_ + (lane & 31), lane);                      \
    }                                                                       \
    float qvn = INFV;                                                       \
    if (comm) qvn = bload(colL, tb_ + BATCH + (lane & 31), lane);           \
    __builtin_amdgcn_sched_barrier(0);                                      \
    ELOAD(NXT, tb_ + BATCH, CLAMP);                                         \
    __builtin_amdgcn_sched_barrier(0);                                      \
    float pbc = INFV;                                                       \
    _Pragma("unroll")                                                       \
    for (int s_ = 0; s_ < BATCH; ++s_) {                                    \
        float e0, e1;                                                       \
        if (DOEXP) { e0 = __expf(-CUR[s_].x); e1 = __expf(-CUR[s_].y); }    \
        else       { e0 = CUR[s_].x;          e1 = CUR[s_].y; }             \
        if (CLAMP && (tb_ + s_ - lane) < 0) { e0 = 0.f; e1 = 0.f; }         \
        float bcur;                                                         \
        if (g == 0)                                                         \
            bcur = (n_ == 0 && s_ == 0) ? 0.f : INFV;   /* (0,0) corner */  \
        else                                                                \
            bcur = __int_as_float(                                          \
                __builtin_amdgcn_readlane(__float_as_int(qv), s_));         \
        const float bpv = (g == 0) ? INFV : ((s_ == 0) ? bprevc : pbc);     \
        const float L1 = lane0 ? bcur : l1s;    /* c[r][col-1]   */         \
        const float L2 = lane0 ? bpv : l2s;     /* c[r-1][col-1] */         \
        const float m0 = fminf(fminf(L1, cur0), L2);                        \
        const float c0 = e0 + m0;                                           \
        const float c1 = e1 + fminf(c0, fminf(cur0, cur1));                 \
        csave[s_] = c1;                                                     \
        const float sh = dpp_wave_shr1(c1);                                 \
        l2s = l1s; l1s = sh;                                                \
        cur0 = c0; cur1 = c1;                                               \
        pbc = bcur;                                                         \
        if (n_ == 129 && s_ == 30) save = c1;   /* final cell r=4095 */     \
    }                                                                       \
    bprevc = pbc;                                                           \
    if (lane == 63) {                                                       \
        _Pragma("unroll")                                                   \
        for (int s_ = 0; s_ < BATCH; ++s_)                                  \
            __hip_atomic_store(colM + (tb_ - 63 + s_),                      \
                               __float_as_uint(csave[s_]),                  \
                               __ATOMIC_RELAXED, __HIP_MEMORY_SCOPE_AGENT); \
    }                                                                       \
    qv = qvn;                                                               \
} while (0)

// ---------------------------------------------------------------------------
// All-register DP: 32 workgroups x ONE 64-lane wave. No LDS, no barriers.
// Strip g owns cols [128g, 128g+128); lane l owns cols 2l, 2l+1; at step t
// lane l computes row r = t - l. Left/diag deps via DPP wave_shr1 chain.
// E arrives by per-lane diagonal global loads issued ONE BATCH AHEAD into a
// ping-pong register pair (eC/eN, 2x-unrolled loop keeps indexing static).
// The compiler's exact per-register s_waitcnt handles load completion; the
// loads have a full batch (~0.5-1us) of slack. Boundary column flows through
// the sentinel-validated agent-scope colbuf exactly as before (lag floor 3
// batches -> 223 periods). Publish: lane63 stores its 32 finished rows at
// batch end (exec-masked; pad region absorbs row<0 / row>=NN).
// ---------------------------------------------------------------------------
template <int DOEXP>
__global__ __launch_bounds__(64) void dtw_dp(const float* __restrict__ S,
                                             float* __restrict__ cost_out,
                                             unsigned* __restrict__ colbuf) {
    const int lane = threadIdx.x;
    const int b = blockIdx.x;
    const int g = ((b & 7) << 2) | (b >> 3);   // XCD-affinity strip remap

    const float* Sg = S + g * SW;
    const unsigned* colL = colbuf + (size_t)(g - 1) * COLPITCH + PAD;
    unsigned* colM = colbuf + (size_t)g * COLPITCH + PAD;
    const bool comm = (g > 0);
    const bool lane0 = (lane == 0);

    float cur0 = INFV, cur1 = INFV;   // my c[r-1][2l], c[r-1][2l+1]
    float l1s = INFV, l2s = INFV;     // lane l-1's c1 from t-1, t-2
    float bprevc = INFV;              // boundary carry (row tb-1)
    float save = 0.f;
    float csave[BATCH];               // lane63's c1 values this batch
    float2 eC[BATCH], eN[BATCH];      // ping-pong E register buffers

    // prologue: boundary rows [0,32) + batch 0's E loads
    float qv = INFV;
    if (comm) qv = bload(colL, lane & 31, lane);
    ELOAD(eC, 0, true);

    // head (row<0 handling), main (clean), tail (row>=NN clamping)
    CSTEP(eC, eN, 0, true);
    CSTEP(eN, eC, 1, true);
    for (int i = 1; i <= 62; ++i) {            // batches 2..125
        CSTEP(eC, eN, 2 * i, false);
        CSTEP(eN, eC, 2 * i + 1, false);
    }
    CSTEP(eC, eN, 126, true);
    CSTEP(eN, eC, 127, true);
    CSTEP(eC, eN, 128, true);
    CSTEP(eN, eC, 129, true);

    if (g == STRIPS - 1 && lane == 63) cost_out[0] = save;
}

// ---------------------------------------------------------------------------
// Fused: E = exp(-D)  AND  acc_grad[i,j] = d[i+1,j+1]+d[i+1,j]+d[i,j+1]-d[i,j]
// with d = exp(-exp(-D)) (zero-padded bottom/right).
// ---------------------------------------------------------------------------
__global__ __launch_bounds__(256) void eg_kernel(const float* __restrict__ D,
                                                 float* __restrict__ E,
                                                 float* __restrict__ G) {
    const int idx = blockIdx.x * 256 + threadIdx.x;
    const int i = idx >> 10;
    const int j = (idx & 1023) << 2;
    if (i >= NN) return;

    const float* row0 = D + (size_t)i * NN + j;
    const bool hasR = (i + 1) < NN;
    const bool hasC = (j + 4) < NN;

    const float4 r0 = *reinterpret_cast<const float4*>(row0);
    float4 r1 = make_float4(0.f, 0.f, 0.f, 0.f);
    if (hasR) r1 = *reinterpret_cast<const float4*>(row0 + NN);
    const float s0 = hasC ? row0[4] : 0.f;
    const float s1 = (hasR && hasC) ? row0[NN + 4] : 0.f;

    const float ex0 = __expf(-r0.x), ex1 = __expf(-r0.y);
    const float ex2 = __expf(-r0.z), ex3 = __expf(-r0.w);
    *reinterpret_cast<float4*>(E + (size_t)i * NN + j) =
        make_float4(ex0, ex1, ex2, ex3);

    const float a0 = __expf(-ex0), a1 = __expf(-ex1);
    const float a2 = __expf(-ex2), a3 = __expf(-ex3);
    const float a4 = hasC ? __expf(-__expf(-s0)) : 0.f;
    const float b0 = hasR ? __expf(-__expf(-r1.x)) : 0.f;
    const float b1 = hasR ? __expf(-__expf(-r1.y)) : 0.f;
    const float b2 = hasR ? __expf(-__expf(-r1.z)) : 0.f;
    const float b3 = hasR ? __expf(-__expf(-r1.w)) : 0.f;
    const float b4 = (hasR && hasC) ? __expf(-__expf(-s1)) : 0.f;

    float* go = G + (size_t)i * NN + j;
    go[0] = b1 + b0 + a1 - a0;
    go[1] = b2 + b1 + a2 - a1;
    go[2] = b3 + b2 + a3 - a2;
    go[3] = b4 + b3 + a4 - a3;
}

// fallback grad (tiny-ws path only)
__device__ __forceinline__ float dfun(float x) { return __expf(-__expf(-x)); }

__global__ __launch_bounds__(256) void dtw_grad_kernel(const float* __restrict__ D,
                                                       float* __restrict__ G) {
    const int idx = blockIdx.x * 256 + threadIdx.x;
    const int i = idx >> 10;
    const int j = (idx & 1023) << 2;
    if (i >= NN) return;

    const float* row0 = D + (size_t)i * NN + j;
    const bool hasR = (i + 1) < NN;
    const bool hasC = (j + 4) < NN;

    const float4 r0 = *reinterpret_cast<const float4*>(row0);
    float4 r1 = make_float4(0.f, 0.f, 0.f, 0.f);
    if (hasR) r1 = *reinterpret_cast<const float4*>(row0 + NN);
    const float s0 = hasC ? row0[4] : 0.f;
    const float s1 = (hasR && hasC) ? row0[NN + 4] : 0.f;

    const float a0 = dfun(r0.x), a1 = dfun(r0.y), a2 = dfun(r0.z), a3 = dfun(r0.w);
    const float a4 = hasC ? dfun(s0) : 0.f;
    const float b0 = hasR ? dfun(r1.x) : 0.f;
    const float b1 = hasR ? dfun(r1.y) : 0.f;
    const float b2 = hasR ? dfun(r1.z) : 0.f;
    const float b3 = hasR ? dfun(r1.w) : 0.f;
    const float b4 = (hasR && hasC) ? dfun(s1) : 0.f;

    float* go = G + (size_t)i * NN + j;
    go[0] = b1 + b0 + a1 - a0;
    go[1] = b2 + b1 + a2 - a1;
    go[2] = b3 + b2 + a3 - a2;
    go[3] = b4 + b3 + a4 - a3;
}

// ---------------------------------------------------------------------------
extern "C" void kernel_launch(void* const* d_in, const int* in_sizes, int n_in,
                              void* d_out, int out_size, void* d_ws, size_t ws_size,
                              hipStream_t stream) {
    (void)in_sizes; (void)n_in; (void)out_size;
    const float* D = (const float*)d_in[0];
    float* out = (float*)d_out;

    const size_t colbytes = (size_t)STRIPS * COLPITCH * sizeof(unsigned);
    const size_t ebytes = (size_t)NN * NN * sizeof(float);
    const int gblocks = (NN * (NN / 4)) / 256;

    if (ws_size >= ebytes + colbytes) {
        float* E = (float*)d_ws;
        unsigned* colbuf = (unsigned*)((char*)d_ws + ebytes);
        (void)hipMemsetAsync(colbuf, 0xFF, colbytes, stream);
        eg_kernel<<<gblocks, 256, 0, stream>>>(D, E, out + 1);
        dtw_dp<0><<<STRIPS, 64, 0, stream>>>(E, out, colbuf);
    } else {
        // tiny-ws fallback: DP reads raw D with on-the-fly exp
        unsigned* colbuf = (ws_size >= colbytes) ? (unsigned*)d_ws
                                                 : (unsigned*)(out + 1);
        (void)hipMemsetAsync(colbuf, 0xFF, colbytes, stream);
        dtw_dp<1><<<STRIPS, 64, 0, stream>>>(D, out, colbuf);
        dtw_grad_kernel<<<gblocks, 256, 0, stream>>>(D, out + 1);
    }
}